// Round 17
// baseline (75.888 us; speedup 1.0000x reference)
//
#include <hip/hip_runtime.h>
#include <hip/hip_bf16.h>
#include <stdint.h>

typedef __attribute__((ext_vector_type(8))) short bf16x8;
typedef __attribute__((ext_vector_type(4))) float f32x4;

__device__ __forceinline__ short f2bf(float x) {
    __hip_bfloat16 h = __float2bfloat16(x);   // native cvt on gfx950 (RNE)
    return __builtin_bit_cast(short, h);
}

__device__ __forceinline__ bf16x8 pack8(f32x4 a, f32x4 b) {
    bf16x8 r;
    r[0] = f2bf(a[0]); r[1] = f2bf(a[1]); r[2] = f2bf(a[2]); r[3] = f2bf(a[3]);
    r[4] = f2bf(b[0]); r[5] = f2bf(b[1]); r[6] = f2bf(b[2]); r[7] = f2bf(b[3]);
    return r;
}

// ---------------------------------------------------------------------------
// Kernel C: repack Wq (1024x48 f32) into bf16 B-fragment layout (for qk).
// ---------------------------------------------------------------------------
__global__ __launch_bounds__(256) void prep_wfrag(const float* __restrict__ Wq,
                                                  short* __restrict__ wfrag) {
    int idx = blockIdx.x * 256 + threadIdx.x;   // 0..49151
    int j    = idx & 7;
    int lane = (idx >> 3) & 63;
    int grp  = idx >> 9;          // ks*3+nf
    int nf   = grp % 3;
    int ks   = grp / 3;
    int k = ks * 32 + ((lane >> 4) << 3) + j;
    int n = nf * 16 + (lane & 15);
    wfrag[idx] = f2bf(Wq[k * 48 + n]);
}

// ---------------------------------------------------------------------------
// Kernel A: qk = Q @ Wq + bq  (M=32768, N=48, K=1024), MFMA 16x16x32 bf16.
// Epilogue scatter-stores bf16 weights into the conv B-frag layout:
//   wB[b][k][dstep(32)][lane(64)][8]   (d = dstep*32 + (lane>>4)*8 + j,
//                                       lane = lkt*16 + h)
// ---------------------------------------------------------------------------
__global__ __launch_bounds__(256) void qk_gemm(const float* __restrict__ Q,
                                               const short* __restrict__ wfrag,
                                               const float* __restrict__ bq,
                                               short* __restrict__ wB) {
    const int l  = threadIdx.x & 63;
    const int w  = threadIdx.x >> 6;
    const int lr = l & 15;
    const int lk = l >> 4;
    const int row0 = blockIdx.x * 64 + w * 16;

    f32x4 acc[3];
    acc[0] = (f32x4){0.f, 0.f, 0.f, 0.f};
    acc[1] = acc[0];
    acc[2] = acc[0];

    const float* qbase = Q + (size_t)(row0 + lr) * 1024 + lk * 8;

    #pragma unroll 4
    for (int ks = 0; ks < 32; ++ks) {
        const float* p = qbase + ks * 32;
        f32x4 q0 = *(const f32x4*)p;
        f32x4 q1 = *(const f32x4*)(p + 4);
        bf16x8 a = pack8(q0, q1);
        const bf16x8* wp = (const bf16x8*)(wfrag + (size_t)ks * 1536 + l * 8);
        acc[0] = __builtin_amdgcn_mfma_f32_16x16x32_bf16(a, wp[0],   acc[0], 0, 0, 0);
        acc[1] = __builtin_amdgcn_mfma_f32_16x16x32_bf16(a, wp[64],  acc[1], 0, 0, 0);
        acc[2] = __builtin_amdgcn_mfma_f32_16x16x32_bf16(a, wp[128], acc[2], 0, 0, 0);
    }

    // C frag: col n = nf*16+lr (f index), row = row0 + lk*4 + r (b*1024+s)
    #pragma unroll
    for (int nf = 0; nf < 3; ++nf) {
        int n = nf * 16 + lr;
        float bias = bq[n];
        int t  = n / 3;          // d low part
        int kk = n - t * 3;      // tap
        #pragma unroll
        for (int r = 0; r < 4; ++r) {
            int row = row0 + lk * 4 + r;
            int b   = row >> 10;
            int h   = (row >> 6) & 15;
            int sp  = row & 63;
            int d   = sp * 16 + t;                    // 0..1023
            // wB element: ((b*3+kk)*32 + d>>5)*512 + ((d>>3)&3)*128 + h*8 + (d&7)
            wB[(((size_t)(b * 3 + kk) << 5) + (d >> 5)) * 512 +
               (((d >> 3) & 3) << 7) + h * 8 + (d & 7)] = f2bf(acc[nf][r] + bias);
        }
    }
}

// ---------------------------------------------------------------------------
// Kernel B v17: TAP-SHIFT conv — a literal qk clone.
// One HBM key stream per lane (row = s0-1+lr, marching in d), 3 L2-hot
// wgt-frag streams, 3 MFMAs/iter SHARING the same A-fragment into 3
// accumulators (one per tap). Tap alignment done ONCE at epilogue:
//   out[s0+j] = acc0[j] + acc1[j+1] + acc2[j+2]
// (in-lane reg shift + __shfl_down(16) for the reg-3 crossings).
// Tile = 14 outputs/wave (rows s0-1..s0+14 = the 16 lr lanes, no gather).
// Boundary rows via zpage pointers. No LDS, no barriers, no atomics;
// stores disjoint. Grid 608 (32b x 19g, XCD-swizzled), 4 waves/block.
// ---------------------------------------------------------------------------
__global__ __launch_bounds__(256) void conv_mfma(const float* __restrict__ Key,
                                                 const short* __restrict__ wB,
                                                 const float* __restrict__ zpage,
                                                 float* __restrict__ out) {
    const int swz = (blockIdx.x & 7) * 76 + (blockIdx.x >> 3);   // bijective, 608=8*76
    const int b   = swz / 19;
    const int g   = swz % 19;
    const int w   = threadIdx.x >> 6;
    const int tile = g * 4 + w;
    if (tile >= 74) return;                     // 74 tiles of 14 outputs cover 1024
    const int l  = threadIdx.x & 63;
    const int lr = l & 15;
    const int lk = l >> 4;
    const int s0 = tile * 14;
    const int krow = s0 - 1 + lr;

    const float* pK = (krow >= 0 && krow < 1024)
        ? Key + ((size_t)b << 20) + (size_t)krow * 1024 + lk * 8
        : zpage + lk * 8;
    const short* pB = wB + (size_t)b * 49152 + l * 8;   // 3*32*512 shorts/batch

    f32x4 acc0 = (f32x4){0.f, 0.f, 0.f, 0.f};
    f32x4 acc1 = acc0, acc2 = acc0;

    #pragma unroll 4
    for (int t = 0; t < 32; ++t) {
        const float* p = pK + t * 32;
        f32x4 k0 = *(const f32x4*)p;
        f32x4 k1 = *(const f32x4*)(p + 4);
        bf16x8 a = pack8(k0, k1);
        bf16x8 b0 = *(const bf16x8*)(pB +         t * 512);
        bf16x8 b1 = *(const bf16x8*)(pB + 16384 + t * 512);
        bf16x8 b2 = *(const bf16x8*)(pB + 32768 + t * 512);
        acc0 = __builtin_amdgcn_mfma_f32_16x16x32_bf16(a, b0, acc0, 0, 0, 0);
        acc1 = __builtin_amdgcn_mfma_f32_16x16x32_bf16(a, b1, acc1, 0, 0, 0);
        acc2 = __builtin_amdgcn_mfma_f32_16x16x32_bf16(a, b2, acc2, 0, 0, 0);
    }

    // epilogue tap-shift combine. C row (= K-row index r) = lk*4+reg, col h = lr.
    float s1_0 = __shfl_down(acc1[0], 16);   // acc1 at row+1 for reg=3
    float s2_0 = __shfl_down(acc2[0], 16);   // acc2 at row+2 for reg=2
    float s2_1 = __shfl_down(acc2[1], 16);   // acc2 at row+2 for reg=3
    float o0 = acc0[0] + acc1[1] + acc2[2];
    float o1 = acc0[1] + acc1[2] + acc2[3];
    float o2 = acc0[2] + acc1[3] + s2_0;
    float o3 = acc0[3] + s1_0   + s2_1;

    float* ob = out + (((size_t)b * 16 + lr) << 10);
    const int j0 = lk * 4;                   // output j = j0+reg, valid j<=13
    if (j0 + 0 <= 13 && s0 + j0 + 0 < 1024) ob[s0 + j0 + 0] = o0;
    if (j0 + 1 <= 13 && s0 + j0 + 1 < 1024) ob[s0 + j0 + 1] = o1;
    if (j0 + 2 <= 13 && s0 + j0 + 2 < 1024) ob[s0 + j0 + 2] = o2;
    if (j0 + 3 <= 13 && s0 + j0 + 3 < 1024) ob[s0 + j0 + 3] = o3;
}

extern "C" void kernel_launch(void* const* d_in, const int* in_sizes, int n_in,
                              void* d_out, int out_size, void* d_ws, size_t ws_size,
                              hipStream_t stream) {
    const float* Q  = (const float*)d_in[0];
    const float* K  = (const float*)d_in[1];
    const float* Wq = (const float*)d_in[4];
    const float* bq = (const float*)d_in[5];
    float* outp = (float*)d_out;

    short* wfrag = (short*)d_ws;                              // 98304 B
    short* wB    = (short*)((char*)d_ws + 98304);             // 3145728 B
    float* zpage = (float*)((char*)d_ws + 98304 + 3145728);   // 4096 B zeros

    hipMemsetAsync(zpage, 0, 4096, stream);
    hipLaunchKernelGGL(prep_wfrag, dim3(192), dim3(256), 0, stream, Wq, wfrag);
    hipLaunchKernelGGL(qk_gemm,    dim3(512), dim3(256), 0, stream, Q, wfrag, bq, wB);
    hipLaunchKernelGGL(conv_mfma,  dim3(608), dim3(256), 0, stream, K, wB, zpage, outp);
}